// Round 4
// baseline (102.444 us; speedup 1.0000x reference)
//
#include <hip/hip_runtime.h>
#include <hip/hip_bf16.h>

// Problem constants (B,G,D,H,K,V) = (4, 2048, 128, 8, 16, 16)
#define GG 2048
#define DD 128
#define HH 8
#define BH 32

typedef _Float16 h2 __attribute__((ext_vector_type(2)));
typedef _Float16 h4 __attribute__((ext_vector_type(4)));
typedef _Float16 h8 __attribute__((ext_vector_type(8)));
typedef __attribute__((ext_vector_type(4))) float f32x4;
typedef unsigned short u16;
typedef unsigned int   u32;
typedef unsigned char  u8;
typedef unsigned long long u64;

// 0.25 (=1/sqrt(16)) * log2(e): folded into W_Q so softmax uses raw exp2.
#define QSCALE 0.36067376022224085f

// ws layout: 6.5 MB
#define OFF_Q  0u           // f16 Qh [BH][G][16] (scaled)                    2 MB
#define OFF_KV (2u << 20)   // u8  KVp [BH][16 tiles][8192]: K(128x16) | V^T  4 MB
#define OFF_M  (6u << 20)   // u8  mbt [16][G][16] transposed mask bits     512 KB

#if __has_builtin(__builtin_amdgcn_exp2f)
#define EXP2F(x) __builtin_amdgcn_exp2f(x)
#else
#define EXP2F(x) exp2f(x)
#endif

// Legacy K=16 f16 MFMA (no underscore before f16 — gfx908-era naming).
#define MFMA16(a, b, c) __builtin_amdgcn_mfma_f32_16x16x16f16(a, b, c, 0, 0, 0)

static __device__ __forceinline__ u16 f16b(float x) {
  return __builtin_bit_cast(u16, (_Float16)x);
}

// ---------------------------------------------------------------------------
// Kernel 1 (fused prep): unchanged from r16 (verified).
//  blocks [0,256):   MFMA projection -> Qh + packed KV tiles.
//  blocks [256,2304): mask int32 -> transposed byte map mbt[g8][q][16],
//                     write-coalesced tiling (256 contiguous B/block).
// ---------------------------------------------------------------------------
__global__ __launch_bounds__(256) void prep_kernel(
    const float* __restrict__ h, const int* __restrict__ mask,
    const float* __restrict__ WQ, const float* __restrict__ WK,
    const float* __restrict__ WV,
    _Float16* __restrict__ Qh, u8* __restrict__ KVp, u8* __restrict__ mbt)
{
  const int blk = blockIdx.x, tid = threadIdx.x;

  if (blk >= 256) {                      // ---- mask -> transposed byte map ----
    int blk2 = blk - 256;                // [0, 2048)
    int q0 = (blk2 >> 4) * 16;           // q tile base
    int g8 = blk2 & 15;                  // key-group (16 bytes = 128 keys)
    int qq = tid >> 4, kk = tid & 15;
    int q = q0 + qq;
    const int* m = mask + (size_t)q * GG + (size_t)(g8 * 16 + kk) * 8;
    int4 m0 = *(const int4*)m;
    int4 m1 = *(const int4*)(m + 4);
    u32 byte = (m0.x > 0) | ((m0.y > 0) << 1) | ((m0.z > 0) << 2) | ((m0.w > 0) << 3)
             | ((m1.x > 0) << 4) | ((m1.y > 0) << 5) | ((m1.z > 0) << 6) | ((m1.w > 0) << 7);
    mbt[(size_t)g8 * (GG * 16) + (size_t)q * 16 + kk] = (u8)byte;
    return;
  }

  // ---- projection: 8 blocks/bh, 4 waves/block, 64 g-rows/wave ----
  __shared__ _Float16 Wl[48 * 136];      // [n 48][d 128 pad 136]
  const int bh = blk >> 3, b = bh >> 3, hh = bh & (HH - 1);

  #pragma unroll
  for (int m = 0; m < 3; ++m) {
    const float* W = (m == 0 ? WQ : (m == 1 ? WK : WV)) + (size_t)hh * DD * 16;
    const float sc = (m == 0) ? QSCALE : 1.0f;
    #pragma unroll
    for (int i = 0; i < 2; ++i) {
      int j4 = i * 256 + tid;
      float4 v = ((const float4*)W)[j4];
      int j = j4 * 4, d = j >> 4, n0 = m * 16 + (j & 15);
      Wl[(n0 + 0) * 136 + d] = (_Float16)(v.x * sc);
      Wl[(n0 + 1) * 136 + d] = (_Float16)(v.y * sc);
      Wl[(n0 + 2) * 136 + d] = (_Float16)(v.z * sc);
      Wl[(n0 + 3) * 136 + d] = (_Float16)(v.w * sc);
    }
  }
  __syncthreads();

  const int wave = tid >> 6, lane = tid & 63;
  const int col = lane & 15, quad = lane >> 4;
  const int g0 = ((blk & 7) * 4 + wave) * 64;
  const float* hb = h + (size_t)b * GG * DD;

  f32x4 acc[4][3];
  #pragma unroll
  for (int mt = 0; mt < 4; ++mt)
    #pragma unroll
    for (int nt = 0; nt < 3; ++nt)
      acc[mt][nt] = (f32x4){0.f, 0.f, 0.f, 0.f};

  #pragma unroll
  for (int s = 0; s < 4; ++s) {
    h8 a[4], bw[3];
    #pragma unroll
    for (int mt = 0; mt < 4; ++mt) {
      const float* src = hb + (size_t)(g0 + mt * 16 + col) * DD + s * 32 + quad * 8;
      float4 x = ((const float4*)src)[0];
      float4 y = ((const float4*)src)[1];
      a[mt] = (h8){ (_Float16)x.x, (_Float16)x.y, (_Float16)x.z, (_Float16)x.w,
                    (_Float16)y.x, (_Float16)y.y, (_Float16)y.z, (_Float16)y.w };
    }
    #pragma unroll
    for (int nt = 0; nt < 3; ++nt)
      bw[nt] = *(const h8*)&Wl[(nt * 16 + col) * 136 + s * 32 + quad * 8];
    #pragma unroll
    for (int mt = 0; mt < 4; ++mt)
      #pragma unroll
      for (int nt = 0; nt < 3; ++nt)
        acc[mt][nt] = __builtin_amdgcn_mfma_f32_16x16x32_f16(a[mt], bw[nt], acc[mt][nt], 0, 0, 0);
  }

  u8* kvb = KVp + (size_t)bh * 16 * 8192;
  #pragma unroll
  for (int mt = 0; mt < 4; ++mt) {
    #pragma unroll
    for (int r = 0; r < 4; ++r) {
      int g = g0 + mt * 16 + quad * 4 + r;
      Qh[((size_t)bh * GG + g) * 16 + col] = (_Float16)acc[mt][0][r];
      int gi = g & 127;
      u8* tb = kvb + (size_t)(g >> 7) * 8192;
      *(u16*)(tb + gi * 32 + col * 2) = f16b(acc[mt][1][r]);                 // K
      *(u16*)(tb + 4096 + col * 256 + ((((gi >> 2) + col) & 31) * 8)
                 + (g & 3) * 2) = f16b(acc[mt][2][r]);                       // V^T swizzled
    }
  }
}

// ---------------------------------------------------------------------------
// Kernel 2: flash attention — r17: whole-bh KV resident in LDS, ZERO loop
// barriers. 1024-thr blocks (16 waves = 8 qt-pairs x 2 key-halves) cover
// 256 q x all 2048 keys; grid = BH*(GG/256) = 256 = 1 block/CU = 4 waves/SIMD
// (TLP unchanged vs r16). All 16 KV tiles (128 KB) staged once up-front
// (8x b128/thread, contiguous, conflict-free), ONE barrier, then 64 straight
// st-iterations/wave: no ds_writes, no vmcnt drains, no barriers — the three
// r16 barrier-drain stalls vanish; compiler free to pipeline ds_reads.
// LDS: 128 KB kv + 17.4 KB Lacc + 1 KB Ll + 256 B LUT = 149.8 KB (<160).
// XCD locality: blocks sharing bh are == mod 8 -> same XCD L2 serves the
// 8x KVp re-read. Inner-st numerics bit-identical to r15/r16 (verified).
// ---------------------------------------------------------------------------
__global__ __launch_bounds__(1024, 1) void attn_kernel(
    const _Float16* __restrict__ Qh, const u8* __restrict__ KVp,
    const u8* __restrict__ mbt, float* __restrict__ out)
{
  __shared__ __align__(16) u8 kv[16 * 8192];   // [tile][K 4KB | V^T 4KB]
  __shared__ float Lacc[16][16][17];           // merge: [q-tile][q][vdim pad]
  __shared__ float Ll[16][16];
  __shared__ __align__(16) f32x4 cmLUT[16];    // 4 mask bits -> C operand
  const int tid = threadIdx.x, wv = tid >> 6, lane = tid & 63;
  const int col = lane & 15, quad = lane >> 4;
  const int qp = wv & 7;               // q-tile-pair index (2 tiles x 16 q)
  const int kh = wv >> 3;              // key half (0: keys 0..1023, 1: rest)
  const int bh = blockIdx.x & 31;      // XCD locality: same bh -> same XCD
  const int qt0 = qp * 2, qt1 = qp * 2 + 1;
  const int qb0 = (blockIdx.x >> 5) * 256 + qt0 * 16;
  const int qb1 = qb0 + 16;

  if (tid < 16) {                      // mask-bits -> C-operand LUT (256 B)
    f32x4 e;
    e[0] = (tid & 1) ? -3000.f : -4.f;
    e[1] = (tid & 2) ? -3000.f : -4.f;
    e[2] = (tid & 4) ? -3000.f : -4.f;
    e[3] = (tid & 8) ? -3000.f : -4.f;
    cmLUT[tid] = e;
  }

  // ---- stage ALL 16 KV tiles (128 KB) : 8x contiguous b128 per thread ----
  const u8* kvsrc = KVp + (size_t)bh * 16 * 8192;
  #pragma unroll
  for (int r = 0; r < 8; ++r)
    *(uint4*)(kv + (size_t)r * 16384 + tid * 16) =
        *(const uint4*)(kvsrc + (size_t)r * 16384 + tid * 16);

  // Q B-frags (16x16x16): n=col, k=quad*4+j -> 8B loads
  const h4 qf0 = *(const h4*)(Qh + ((size_t)bh * GG + qb0 + col) * 16 + quad * 4);
  const h4 qf1 = *(const h4*)(Qh + ((size_t)bh * GG + qb1 + col) * 16 + quad * 4);
  const u8* mrow0 = mbt + (size_t)(qb0 + col) * 16;
  const u8* mrow1 = mbt + (size_t)(qb1 + col) * 16;

  f32x4 acc0 = {0.f,0.f,0.f,0.f}, lacc0 = {0.f,0.f,0.f,0.f};
  f32x4 acc1 = {0.f,0.f,0.f,0.f}, lacc1 = {0.f,0.f,0.f,0.f};
  const h4 ones = {(_Float16)1.f, (_Float16)1.f, (_Float16)1.f, (_Float16)1.f};
  const int shq = quad * 4;

  // V^T swizzled read offsets within a tile: constant across it -> hoist
  int voff[8];
  #pragma unroll
  for (int st = 0; st < 8; ++st)
    voff[st] = 4096 + col * 256 + (((st * 4 + quad + col) & 31) * 8);

  const size_t tstep = (size_t)(GG * 16);
  uint4 mv0 = *(const uint4*)(mrow0 + (size_t)(kh * 8) * tstep);
  uint4 mv1 = *(const uint4*)(mrow1 + (size_t)(kh * 8) * tstep);
  __syncthreads();                     // the ONLY pre-merge barrier

  #pragma unroll 2
  for (int it = 0; it < 8; ++it) {
    uint4 nm0, nm1;
    if (it < 7) {                      // mask prefetch (regs only)
      nm0 = *(const uint4*)(mrow0 + (size_t)(kh * 8 + it + 1) * tstep);
      nm1 = *(const uint4*)(mrow1 + (size_t)(kh * 8 + it + 1) * tstep);
    }

    const u8* cur = kv + (size_t)(kh * 8 + it) * 8192;
    const _Float16* ldsK = (const _Float16*)cur;
    u64 a0 = ((u64)mv0.x | ((u64)mv0.y << 32)) >> shq;   // qt0 keys 0..63
    u64 a1 = ((u64)mv0.z | ((u64)mv0.w << 32)) >> shq;   // qt0 keys 64..127
    u64 b0 = ((u64)mv1.x | ((u64)mv1.y << 32)) >> shq;   // qt1 keys 0..63
    u64 b1 = ((u64)mv1.z | ((u64)mv1.w << 32)) >> shq;   // qt1 keys 64..127

    #pragma unroll
    for (int st = 0; st < 8; ++st) {
      // shared K row + chunk-swizzled V^T row (one ds_read_b64 each, both qt)
      h4 kf = *(const h4*)(ldsK + (size_t)(st * 16 + col) * 16 + quad * 4);
      h4 vf = *(const h4*)(cur + voff[st]);

      // mask -> C operand via LDS LUT (masked -> -3000: exp2 underflows to
      // exact +0; unmasked -> -4 uniform shift, cancels in softmax)
      u32 bitsA = (u32)(((st < 4) ? a0 : a1) >> ((st & 3) * 16)) & 0xFu;
      u32 bitsB = (u32)(((st < 4) ? b0 : b1) >> ((st & 3) * 16)) & 0xFu;
      const f32x4 cmA = cmLUT[bitsA];
      const f32x4 cmB = cmLUT[bitsB];

      f32x4 s0 = MFMA16(kf, qf0, cmA);         // S^T[key=quad*4+r][q=col]
      f32x4 s1 = MFMA16(kf, qf1, cmB);
      float p0 = EXP2F(s0[0]);
      float p1 = EXP2F(s0[1]);
      float p2 = EXP2F(s0[2]);
      float p3 = EXP2F(s0[3]);
      float r0 = EXP2F(s1[0]);
      float r1 = EXP2F(s1[1]);
      float r2 = EXP2F(s1[2]);
      float r3 = EXP2F(s1[3]);

      h2 a01 = __builtin_bit_cast(h2, __builtin_amdgcn_cvt_pkrtz(p0, p1));
      h2 a23 = __builtin_bit_cast(h2, __builtin_amdgcn_cvt_pkrtz(p2, p3));
      h4 pf0 = __builtin_shufflevector(a01, a23, 0, 1, 2, 3);
      h2 c01 = __builtin_bit_cast(h2, __builtin_amdgcn_cvt_pkrtz(r0, r1));
      h2 c23 = __builtin_bit_cast(h2, __builtin_amdgcn_cvt_pkrtz(r2, r3));
      h4 pf1 = __builtin_shufflevector(c01, c23, 0, 1, 2, 3);

      acc0  = MFMA16(vf, pf0, acc0);           // O^T[vdim][q]
      acc1  = MFMA16(vf, pf1, acc1);
      lacc0 = MFMA16(ones, pf0, lacc0);        // denominators (MFMA pipe)
      lacc1 = MFMA16(ones, pf1, lacc1);
    }

    if (it < 7) { mv0 = nm0; mv1 = nm1; }
  }

  // split-K merge: half 0 publishes partials, half 1 combines + stores
  const float l0 = lacc0[0], l1 = lacc1[0];    // sum_k P[k][col], this half
  if (kh == 0) {
    #pragma unroll
    for (int r = 0; r < 4; ++r) {
      Lacc[qt0][col][shq + r] = acc0[r];
      Lacc[qt1][col][shq + r] = acc1[r];
    }
    if (quad == 0) { Ll[qt0][col] = l0; Ll[qt1][col] = l1; }
  }
  __syncthreads();
  if (kh == 1) {
    float la0 = Ll[qt0][col] + l0;
    float ra0 = (la0 > 0.f) ? (1.f / la0) : 0.f;  // all-masked row -> 0 (ref)
    float4 o0;
    o0.x = (Lacc[qt0][col][shq + 0] + acc0[0]) * ra0;
    o0.y = (Lacc[qt0][col][shq + 1] + acc0[1]) * ra0;
    o0.z = (Lacc[qt0][col][shq + 2] + acc0[2]) * ra0;
    o0.w = (Lacc[qt0][col][shq + 3] + acc0[3]) * ra0;
    *(float4*)(out + ((size_t)bh * GG + qb0 + col) * 16 + shq) = o0;

    float la1 = Ll[qt1][col] + l1;
    float ra1 = (la1 > 0.f) ? (1.f / la1) : 0.f;
    float4 o1;
    o1.x = (Lacc[qt1][col][shq + 0] + acc1[0]) * ra1;
    o1.y = (Lacc[qt1][col][shq + 1] + acc1[1]) * ra1;
    o1.z = (Lacc[qt1][col][shq + 2] + acc1[2]) * ra1;
    o1.w = (Lacc[qt1][col][shq + 3] + acc1[3]) * ra1;
    *(float4*)(out + ((size_t)bh * GG + qb1 + col) * 16 + shq) = o1;
  }
}

// ---------------------------------------------------------------------------
extern "C" void kernel_launch(void* const* d_in, const int* in_sizes, int n_in,
                              void* d_out, int out_size, void* d_ws, size_t ws_size,
                              hipStream_t stream) {
  const float* h    = (const float*)d_in[0];
  const int*   mask = (const int*)d_in[1];
  const float* WQ   = (const float*)d_in[2];
  const float* WK   = (const float*)d_in[3];
  const float* WV   = (const float*)d_in[4];
  float* out = (float*)d_out;
  char* ws = (char*)d_ws;     // uses 6.5 MB
  _Float16* Qh  = (_Float16*)(ws + OFF_Q);
  u8*       KVp = (u8*)(ws + OFF_KV);
  u8*       mbt = (u8*)(ws + OFF_M);

  hipLaunchKernelGGL(prep_kernel, dim3(256 + GG * GG / (256 * 8)), dim3(256), 0, stream,
                     h, mask, WQ, WK, WV, Qh, KVp, mbt);
  hipLaunchKernelGGL(attn_kernel, dim3(BH * (GG / 256)), dim3(1024), 0, stream,
                     Qh, KVp, mbt, out);
}

// Round 5
// 101.657 us; speedup vs baseline: 1.0077x; 1.0077x over previous
//
#include <hip/hip_runtime.h>
#include <hip/hip_bf16.h>

// Problem constants (B,G,D,H,K,V) = (4, 2048, 128, 8, 16, 16)
#define GG 2048
#define DD 128
#define HH 8
#define BH 32

typedef _Float16 h2 __attribute__((ext_vector_type(2)));
typedef _Float16 h4 __attribute__((ext_vector_type(4)));
typedef _Float16 h8 __attribute__((ext_vector_type(8)));
typedef __attribute__((ext_vector_type(4))) float f32x4;
typedef unsigned short u16;
typedef unsigned int   u32;
typedef unsigned char  u8;
typedef unsigned long long u64;

// 0.25 (=1/sqrt(16)) * log2(e): folded into W_Q so softmax uses raw exp2.
#define QSCALE 0.36067376022224085f

// ws layout: 6.5 MB
#define OFF_Q  0u           // f16 Qh [BH][G][16] (scaled)                    2 MB
#define OFF_KV (2u << 20)   // u8  KVp [BH][16 tiles][8192]: K(128x16) | V^T  4 MB
#define OFF_M  (6u << 20)   // u8  mbt [16][G][16] transposed mask bits     512 KB

#if __has_builtin(__builtin_amdgcn_exp2f)
#define EXP2F(x) __builtin_amdgcn_exp2f(x)
#else
#define EXP2F(x) exp2f(x)
#endif

// Legacy K=16 f16 MFMA (no underscore before f16 — gfx908-era naming).
#define MFMA16(a, b, c) __builtin_amdgcn_mfma_f32_16x16x16f16(a, b, c, 0, 0, 0)

static __device__ __forceinline__ u16 f16b(float x) {
  return __builtin_bit_cast(u16, (_Float16)x);
}

// ---------------------------------------------------------------------------
// Kernel 1 (fused prep):
//  blocks [0,256):   MFMA projection -> Qh + packed KV tiles (verified,
//                    unchanged).
//  blocks [256,2304): mask int32 -> transposed byte map mbt[g8][q][16].
//    r16: retiled so each block covers (16 q) x (one g8 group): writes are
//    256 contiguous bytes/block (was 16x16B at 32KB strides -> cache-line
//    write amplification); reads stay in 512B contiguous segments.
// ---------------------------------------------------------------------------
__global__ __launch_bounds__(256) void prep_kernel(
    const float* __restrict__ h, const int* __restrict__ mask,
    const float* __restrict__ WQ, const float* __restrict__ WK,
    const float* __restrict__ WV,
    _Float16* __restrict__ Qh, u8* __restrict__ KVp, u8* __restrict__ mbt)
{
  const int blk = blockIdx.x, tid = threadIdx.x;

  if (blk >= 256) {                      // ---- mask -> transposed byte map ----
    int blk2 = blk - 256;                // [0, 2048)
    int q0 = (blk2 >> 4) * 16;           // q tile base
    int g8 = blk2 & 15;                  // key-group (16 bytes = 128 keys)
    int qq = tid >> 4, kk = tid & 15;
    int q = q0 + qq;
    const int* m = mask + (size_t)q * GG + (size_t)(g8 * 16 + kk) * 8;
    int4 m0 = *(const int4*)m;
    int4 m1 = *(const int4*)(m + 4);
    u32 byte = (m0.x > 0) | ((m0.y > 0) << 1) | ((m0.z > 0) << 2) | ((m0.w > 0) << 3)
             | ((m1.x > 0) << 4) | ((m1.y > 0) << 5) | ((m1.z > 0) << 6) | ((m1.w > 0) << 7);
    mbt[(size_t)g8 * (GG * 16) + (size_t)q * 16 + kk] = (u8)byte;
    return;
  }

  // ---- projection: 8 blocks/bh, 4 waves/block, 64 g-rows/wave ----
  __shared__ _Float16 Wl[48 * 136];      // [n 48][d 128 pad 136]
  const int bh = blk >> 3, b = bh >> 3, hh = bh & (HH - 1);

  #pragma unroll
  for (int m = 0; m < 3; ++m) {
    const float* W = (m == 0 ? WQ : (m == 1 ? WK : WV)) + (size_t)hh * DD * 16;
    const float sc = (m == 0) ? QSCALE : 1.0f;
    #pragma unroll
    for (int i = 0; i < 2; ++i) {
      int j4 = i * 256 + tid;
      float4 v = ((const float4*)W)[j4];
      int j = j4 * 4, d = j >> 4, n0 = m * 16 + (j & 15);
      Wl[(n0 + 0) * 136 + d] = (_Float16)(v.x * sc);
      Wl[(n0 + 1) * 136 + d] = (_Float16)(v.y * sc);
      Wl[(n0 + 2) * 136 + d] = (_Float16)(v.z * sc);
      Wl[(n0 + 3) * 136 + d] = (_Float16)(v.w * sc);
    }
  }
  __syncthreads();

  const int wave = tid >> 6, lane = tid & 63;
  const int col = lane & 15, quad = lane >> 4;
  const int g0 = ((blk & 7) * 4 + wave) * 64;
  const float* hb = h + (size_t)b * GG * DD;

  f32x4 acc[4][3];
  #pragma unroll
  for (int mt = 0; mt < 4; ++mt)
    #pragma unroll
    for (int nt = 0; nt < 3; ++nt)
      acc[mt][nt] = (f32x4){0.f, 0.f, 0.f, 0.f};

  #pragma unroll
  for (int s = 0; s < 4; ++s) {
    h8 a[4], bw[3];
    #pragma unroll
    for (int mt = 0; mt < 4; ++mt) {
      const float* src = hb + (size_t)(g0 + mt * 16 + col) * DD + s * 32 + quad * 8;
      float4 x = ((const float4*)src)[0];
      float4 y = ((const float4*)src)[1];
      a[mt] = (h8){ (_Float16)x.x, (_Float16)x.y, (_Float16)x.z, (_Float16)x.w,
                    (_Float16)y.x, (_Float16)y.y, (_Float16)y.z, (_Float16)y.w };
    }
    #pragma unroll
    for (int nt = 0; nt < 3; ++nt)
      bw[nt] = *(const h8*)&Wl[(nt * 16 + col) * 136 + s * 32 + quad * 8];
    #pragma unroll
    for (int mt = 0; mt < 4; ++mt)
      #pragma unroll
      for (int nt = 0; nt < 3; ++nt)
        acc[mt][nt] = __builtin_amdgcn_mfma_f32_16x16x32_f16(a[mt], bw[nt], acc[mt][nt], 0, 0, 0);
  }

  u8* kvb = KVp + (size_t)bh * 16 * 8192;
  #pragma unroll
  for (int mt = 0; mt < 4; ++mt) {
    #pragma unroll
    for (int r = 0; r < 4; ++r) {
      int g = g0 + mt * 16 + quad * 4 + r;
      Qh[((size_t)bh * GG + g) * 16 + col] = (_Float16)acc[mt][0][r];
      int gi = g & 127;
      u8* tb = kvb + (size_t)(g >> 7) * 8192;
      *(u16*)(tb + gi * 32 + col * 2) = f16b(acc[mt][1][r]);                 // K
      *(u16*)(tb + 4096 + col * 256 + ((((gi >> 2) + col) & 31) * 8)
                 + (g & 3) * 2) = f16b(acc[mt][2][r]);                       // V^T swizzled
    }
  }
}

// ---------------------------------------------------------------------------
// Kernel 2: flash attention — r16 structure (verified best, 101.87 µs):
// 2 q-tiles per wave (shared kf/vf LDS reads), 2-tile-deep staging, 4
// barriers. r17's whole-bh-resident zero-barrier variant REGRESSED (+0.5 µs:
// 1 block/CU exposes the 128 KB staging prologue serially and loses tail
// overlap) — reverted. kv[pair parity][it&1]: while computing pair p, both
// tiles of pair p+1 load to regs (issued at pair top), written + ONE barrier
// at pair end; written buffer was last read in pair p-1 -> race-free.
// LDS: 64KB kv + 8.7KB merge + LUT = 73.5KB -> 2 blocks/CU, 4 waves/SIMD.
// ---------------------------------------------------------------------------
__global__ __launch_bounds__(512, 4) void attn_kernel(
    const _Float16* __restrict__ Qh, const u8* __restrict__ KVp,
    const u8* __restrict__ mbt, float* __restrict__ out)
{
  __shared__ __align__(16) u8 kv[2][2][16384]; // [pair parity][it&1][8KB half0|half1]
  __shared__ float Lacc[8][16][17];            // merge: [q-tile][q][vdim pad]
  __shared__ float Ll[8][16];
  __shared__ __align__(16) f32x4 cmLUT[16];    // 4 mask bits -> C operand
  const int tid = threadIdx.x, wv = tid >> 6, lane = tid & 63;
  const int col = lane & 15, quad = lane >> 4;
  const int qp = wv & 3;               // q-tile-pair index (2 tiles x 16 q)
  const int kh = wv >> 2;              // key half (0: keys 0..1023, 1: rest)
  const int bh = blockIdx.x & 31;      // XCD swizzle: same bh -> same XCD
  const int qt0 = qp * 2, qt1 = qp * 2 + 1;
  const int qb0 = (blockIdx.x >> 5) * 128 + qt0 * 16;
  const int qb1 = qb0 + 16;

  if (tid < 16) {                      // mask-bits -> C-operand LUT (256 B)
    f32x4 e;
    e[0] = (tid & 1) ? -3000.f : -4.f;
    e[1] = (tid & 2) ? -3000.f : -4.f;
    e[2] = (tid & 4) ? -3000.f : -4.f;
    e[3] = (tid & 8) ? -3000.f : -4.f;
    cmLUT[tid] = e;
  }

  // Q B-frags (16x16x16): n=col, k=quad*4+j -> 8B loads
  const h4 qf0 = *(const h4*)(Qh + ((size_t)bh * GG + qb0 + col) * 16 + quad * 4);
  const h4 qf1 = *(const h4*)(Qh + ((size_t)bh * GG + qb1 + col) * 16 + quad * 4);
  const u8* kvsrc = KVp + (size_t)bh * 16 * 8192;
  const u8* mrow0 = mbt + (size_t)(qb0 + col) * 16;
  const u8* mrow1 = mbt + (size_t)(qb1 + col) * 16;

  f32x4 acc0 = {0.f,0.f,0.f,0.f}, lacc0 = {0.f,0.f,0.f,0.f};
  f32x4 acc1 = {0.f,0.f,0.f,0.f}, lacc1 = {0.f,0.f,0.f,0.f};
  const h4 ones = {(_Float16)1.f, (_Float16)1.f, (_Float16)1.f, (_Float16)1.f};
  const int shq = quad * 4;

  // V^T swizzled read offsets: constant across it -> hoist
  int voff[8];
  #pragma unroll
  for (int st = 0; st < 8; ++st)
    voff[st] = kh * 8192 + 4096 + col * 256 + (((st * 4 + quad + col) & 31) * 8);
  const int koff = kh * 8192;

  // staging role: threads 0-255 stage half-0 tiles (it), 256-511 half-1 (8+it)
  // each thread moves 32 B per tile (two uint4)
  const int sh2 = tid >> 8, stid = tid & 255;

  // prologue: stage pair 0 (tiles {0,1} of this half) + tile-0 masks
  {
    const u8* s0 = kvsrc + (size_t)(sh2 * 8 + 0) * 8192;
    const u8* s1 = kvsrc + (size_t)(sh2 * 8 + 1) * 8192;
    *(uint4*)(kv[0][0] + sh2 * 8192 + stid * 16)        = *(const uint4*)(s0 + stid * 16);
    *(uint4*)(kv[0][0] + sh2 * 8192 + 4096 + stid * 16) = *(const uint4*)(s0 + 4096 + stid * 16);
    *(uint4*)(kv[0][1] + sh2 * 8192 + stid * 16)        = *(const uint4*)(s1 + stid * 16);
    *(uint4*)(kv[0][1] + sh2 * 8192 + 4096 + stid * 16) = *(const uint4*)(s1 + 4096 + stid * 16);
  }
  const size_t tstep = (size_t)(GG * 16);
  uint4 mv0 = *(const uint4*)(mrow0 + (size_t)(kh * 8) * tstep);
  uint4 mv1 = *(const uint4*)(mrow1 + (size_t)(kh * 8) * tstep);
  __syncthreads();

  #pragma unroll
  for (int p = 0; p < 4; ++p) {
    uint4 nsA0, nsA1, nsB0, nsB1;
    if (p < 3) {                       // prefetch BOTH tiles of next pair
      const u8* sA = kvsrc + (size_t)(sh2 * 8 + 2 * p + 2) * 8192;
      nsA0 = *(const uint4*)(sA + stid * 16);
      nsA1 = *(const uint4*)(sA + 4096 + stid * 16);
      const u8* sB = sA + 8192;
      nsB0 = *(const uint4*)(sB + stid * 16);
      nsB1 = *(const uint4*)(sB + 4096 + stid * 16);
    }

    #pragma unroll
    for (int hh2 = 0; hh2 < 2; ++hh2) {
      const int it = 2 * p + hh2;
      uint4 nm0, nm1;
      if (it < 7) {                    // mask prefetch (regs, no barrier)
        nm0 = *(const uint4*)(mrow0 + (size_t)(kh * 8 + it + 1) * tstep);
        nm1 = *(const uint4*)(mrow1 + (size_t)(kh * 8 + it + 1) * tstep);
      }

      const u8* cur = kv[p & 1][hh2];
      const _Float16* ldsK = (const _Float16*)(cur + koff);
      u64 a0 = ((u64)mv0.x | ((u64)mv0.y << 32)) >> shq;   // qt0 keys 0..63
      u64 a1 = ((u64)mv0.z | ((u64)mv0.w << 32)) >> shq;   // qt0 keys 64..127
      u64 b0 = ((u64)mv1.x | ((u64)mv1.y << 32)) >> shq;   // qt1 keys 0..63
      u64 b1 = ((u64)mv1.z | ((u64)mv1.w << 32)) >> shq;   // qt1 keys 64..127

      #pragma unroll
      for (int st = 0; st < 8; ++st) {
        // shared K row + chunk-swizzled V^T row (one ds_read_b64 each)
        h4 kf = *(const h4*)(ldsK + (size_t)(st * 16 + col) * 16 + quad * 4);
        h4 vf = *(const h4*)(cur + voff[st]);

        // mask -> C operand via LDS LUT (masked -> -3000: exp2 underflows to
        // exact +0; unmasked -> -4 uniform shift, cancels in softmax)
        u32 bitsA = (u32)(((st < 4) ? a0 : a1) >> ((st & 3) * 16)) & 0xFu;
        u32 bitsB = (u32)(((st < 4) ? b0 : b1) >> ((st & 3) * 16)) & 0xFu;
        const f32x4 cmA = cmLUT[bitsA];
        const f32x4 cmB = cmLUT[bitsB];

        f32x4 s0 = MFMA16(kf, qf0, cmA);         // S^T[key=quad*4+r][q=col]
        f32x4 s1 = MFMA16(kf, qf1, cmB);
        float p0 = EXP2F(s0[0]);
        float p1 = EXP2F(s0[1]);
        float p2 = EXP2F(s0[2]);
        float p3 = EXP2F(s0[3]);
        float r0 = EXP2F(s1[0]);
        float r1 = EXP2F(s1[1]);
        float r2 = EXP2F(s1[2]);
        float r3 = EXP2F(s1[3]);

        h2 a01 = __builtin_bit_cast(h2, __builtin_amdgcn_cvt_pkrtz(p0, p1));
        h2 a23 = __builtin_bit_cast(h2, __builtin_amdgcn_cvt_pkrtz(p2, p3));
        h4 pf0 = __builtin_shufflevector(a01, a23, 0, 1, 2, 3);
        h2 c01 = __builtin_bit_cast(h2, __builtin_amdgcn_cvt_pkrtz(r0, r1));
        h2 c23 = __builtin_bit_cast(h2, __builtin_amdgcn_cvt_pkrtz(r2, r3));
        h4 pf1 = __builtin_shufflevector(c01, c23, 0, 1, 2, 3);

        acc0  = MFMA16(vf, pf0, acc0);           // O^T[vdim][q]
        acc1  = MFMA16(vf, pf1, acc1);
        lacc0 = MFMA16(ones, pf0, lacc0);        // denominators (MFMA pipe)
        lacc1 = MFMA16(ones, pf1, lacc1);
      }

      if (it < 7) { mv0 = nm0; mv1 = nm1; }
    }

    if (p < 3) {                       // write next pair + ONE barrier
      u8* dA = kv[(p + 1) & 1][0] + sh2 * 8192;
      *(uint4*)(dA + stid * 16)        = nsA0;
      *(uint4*)(dA + 4096 + stid * 16) = nsA1;
      u8* dB = kv[(p + 1) & 1][1] + sh2 * 8192;
      *(uint4*)(dB + stid * 16)        = nsB0;
      *(uint4*)(dB + 4096 + stid * 16) = nsB1;
      __syncthreads();
    }
  }

  // split-K merge: half 0 publishes partials, half 1 combines + stores
  const float l0 = lacc0[0], l1 = lacc1[0];      // sum_k P[k][col], this half
  if (kh == 0) {
    #pragma unroll
    for (int r = 0; r < 4; ++r) {
      Lacc[qt0][col][shq + r] = acc0[r];
      Lacc[qt1][col][shq + r] = acc1[r];
    }
    if (quad == 0) { Ll[qt0][col] = l0; Ll[qt1][col] = l1; }
  }
  __syncthreads();
  if (kh == 1) {
    float la0 = Ll[qt0][col] + l0;
    float ra0 = (la0 > 0.f) ? (1.f / la0) : 0.f;  // all-masked row -> 0 (ref)
    float4 o0;
    o0.x = (Lacc[qt0][col][shq + 0] + acc0[0]) * ra0;
    o0.y = (Lacc[qt0][col][shq + 1] + acc0[1]) * ra0;
    o0.z = (Lacc[qt0][col][shq + 2] + acc0[2]) * ra0;
    o0.w = (Lacc[qt0][col][shq + 3] + acc0[3]) * ra0;
    *(float4*)(out + ((size_t)bh * GG + qb0 + col) * 16 + shq) = o0;

    float la1 = Ll[qt1][col] + l1;
    float ra1 = (la1 > 0.f) ? (1.f / la1) : 0.f;
    float4 o1;
    o1.x = (Lacc[qt1][col][shq + 0] + acc1[0]) * ra1;
    o1.y = (Lacc[qt1][col][shq + 1] + acc1[1]) * ra1;
    o1.z = (Lacc[qt1][col][shq + 2] + acc1[2]) * ra1;
    o1.w = (Lacc[qt1][col][shq + 3] + acc1[3]) * ra1;
    *(float4*)(out + ((size_t)bh * GG + qb1 + col) * 16 + shq) = o1;
  }
}

// ---------------------------------------------------------------------------
extern "C" void kernel_launch(void* const* d_in, const int* in_sizes, int n_in,
                              void* d_out, int out_size, void* d_ws, size_t ws_size,
                              hipStream_t stream) {
  const float* h    = (const float*)d_in[0];
  const int*   mask = (const int*)d_in[1];
  const float* WQ   = (const float*)d_in[2];
  const float* WK   = (const float*)d_in[3];
  const float* WV   = (const float*)d_in[4];
  float* out = (float*)d_out;
  char* ws = (char*)d_ws;     // uses 6.5 MB
  _Float16* Qh  = (_Float16*)(ws + OFF_Q);
  u8*       KVp = (u8*)(ws + OFF_KV);
  u8*       mbt = (u8*)(ws + OFF_M);

  hipLaunchKernelGGL(prep_kernel, dim3(256 + GG * GG / (256 * 8)), dim3(256), 0, stream,
                     h, mask, WQ, WK, WV, Qh, KVp, mbt);
  hipLaunchKernelGGL(attn_kernel, dim3(BH * (GG / 128)), dim3(512), 0, stream,
                     Qh, KVp, mbt, out);
}